// Round 4
// baseline (316.241 us; speedup 1.0000x reference)
//
#include <hip/hip_runtime.h>

typedef float f32x4 __attribute__((ext_vector_type(4)));
typedef short bf16x8 __attribute__((ext_vector_type(8)));
typedef unsigned short u16;
typedef u16 u16x8 __attribute__((ext_vector_type(8)));
typedef unsigned int u32;

#define B 4
#define C 256
#define K 64
#define NN 4096
#define W3C 768
#define CP 264   // padded LDS row (shorts) for 256-col tiles
#define SP 72    // padded LDS row (shorts) for 64-col sigmaT tile

__device__ __forceinline__ u16 bf_hi(float f) {
    unsigned u = __float_as_uint(f);
    u += 0x7FFFu + ((u >> 16) & 1u);
    return (u16)(u >> 16);
}
__device__ __forceinline__ float bf_f(u16 s) { return __uint_as_float(((unsigned)s) << 16); }

// ================= mega-prep: x->hi/lo, w_cat->hi/lo, mu init =================
// grid 2400 blocks x 256 threads
__global__ void k_prep(const float* __restrict__ x, const float* __restrict__ mu0,
                       const float* __restrict__ w_cat,
                       u16* __restrict__ xch, u16* __restrict__ xcl,
                       u16* __restrict__ wch, u16* __restrict__ wcl,
                       u16* __restrict__ muth, u16* __restrict__ mutl) {
    int blk = blockIdx.x, tid = threadIdx.x;
    if (blk < 2048) {
        int i = blk * 256 + tid;   // 8 elems/thread, covers B*C*NN
        const float4* s4 = (const float4*)(x + (size_t)i * 8);
        float4 a = s4[0], bq = s4[1];
        float v[8] = {a.x, a.y, a.z, a.w, bq.x, bq.y, bq.z, bq.w};
        u16x8 hv, lv;
        #pragma unroll
        for (int j = 0; j < 8; j++) { u16 hh = bf_hi(v[j]); hv[j] = hh; lv[j] = bf_hi(v[j] - bf_f(hh)); }
        *(u16x8*)(xch + (size_t)i * 8) = hv;
        *(u16x8*)(xcl + (size_t)i * 8) = lv;
    } else if (blk < 2144) {
        int i = (blk - 2048) * 256 + tid;  // covers C*W3C/8
        const float4* s4 = (const float4*)(w_cat + (size_t)i * 8);
        float4 a = s4[0], bq = s4[1];
        float v[8] = {a.x, a.y, a.z, a.w, bq.x, bq.y, bq.z, bq.w};
        u16x8 hv, lv;
        #pragma unroll
        for (int j = 0; j < 8; j++) { u16 hh = bf_hi(v[j]); hv[j] = hh; lv[j] = bf_hi(v[j] - bf_f(hh)); }
        *(u16x8*)(wch + (size_t)i * 8) = hv;
        *(u16x8*)(wcl + (size_t)i * 8) = lv;
    } else {
        int g = (blk - 2144) * 256 + tid;  // (b*K+k)*C+c linear, 65536 total
        int kq = (g >> 8) & 63, cq = g & 255;
        float v = mu0[cq * K + kq];
        u16 hh = bf_hi(v);
        muth[g] = hh;
        mutl[g] = bf_hi(v - bf_f(hh));
    }
}

// ================= fused E+M step =================
// grid (64, B), block 256, dynamic LDS 157,952 B (1 block/CU)
__global__ __launch_bounds__(256) void k_em(
        const u16* __restrict__ xch, const u16* __restrict__ xcl,
        const u16* __restrict__ muth, const u16* __restrict__ mutl,
        float* __restrict__ tpart, float* __restrict__ dpart,
        u16* __restrict__ sig_out, int pv, int write_sig)
{
    extern __shared__ char smem[];
    u16* sxh = (u16*)smem;            // [64][CP] x tile hi: rows n_local, cols c
    u16* sxl = sxh + 64 * CP;
    u16* smh = sxl + 64 * CP;         // [64][CP] muT hi: rows k, cols c
    u16* sml = smh + 64 * CP;
    u16* sTh = sml + 64 * CP;         // [64][SP] sigmaT hi: rows k, cols n_local
    u16* sTl = sTh + 64 * SP;
    float* redf = (float*)(sTl + 64 * SP);  // 1088 floats

    const int ch = blockIdx.x, b = blockIdx.y, tid = threadIdx.x;
    const int n0 = ch * 64;

    // ---- stage x tile [64n][256c] hi/lo via in-block transpose from c-major ----
    {
        int p2 = tid & 127, h = tid >> 7;   // c-pair index, n-half
        #pragma unroll
        for (int nc = 0; nc < 4; nc++) {
            int nrow = h * 32 + nc * 8;
            u16x8 a0h = *(const u16x8*)&xch[((size_t)(b * C + 2 * p2)) * NN + n0 + nrow];
            u16x8 a1h = *(const u16x8*)&xch[((size_t)(b * C + 2 * p2 + 1)) * NN + n0 + nrow];
            u16x8 a0l = *(const u16x8*)&xcl[((size_t)(b * C + 2 * p2)) * NN + n0 + nrow];
            u16x8 a1l = *(const u16x8*)&xcl[((size_t)(b * C + 2 * p2 + 1)) * NN + n0 + nrow];
            #pragma unroll
            for (int j = 0; j < 8; j++) {
                *(u32*)&sxh[(nrow + j) * CP + 2 * p2] = (u32)a0h[j] | ((u32)a1h[j] << 16);
                *(u32*)&sxl[(nrow + j) * CP + 2 * p2] = (u32)a0l[j] | ((u32)a1l[j] << 16);
            }
        }
    }
    // ---- stage muT [64k][256c] hi/lo (coalesced) ----
    {
        size_t mbase = ((size_t)(b * K)) * C;
        for (int t = tid; t < 2048; t += 256) {
            int r = t >> 5, cof = (t & 31) * 8;
            *(u16x8*)&smh[r * CP + cof] = *(const u16x8*)&muth[mbase + (size_t)r * C + cof];
            *(u16x8*)&sml[r * CP + cof] = *(const u16x8*)&mutl[mbase + (size_t)r * C + cof];
        }
    }
    __syncthreads();

    const int wid = tid >> 6, l = tid & 63, lg = l >> 4, lr = l & 15;
    f32x4 z4 = {0.f, 0.f, 0.f, 0.f};

    // ---- E: logits[n][k] = sum_c x[n][c] * mu[k][c]  (3-term hi/lo) ----
    f32x4 acc[4] = {z4, z4, z4, z4};
    for (int cc = 0; cc < 8; cc++) {
        int co = cc * 32 + lg * 8;
        bf16x8 Ah = *(bf16x8*)&sxh[(wid * 16 + lr) * CP + co];
        bf16x8 Al = *(bf16x8*)&sxl[(wid * 16 + lr) * CP + co];
        #pragma unroll
        for (int kt = 0; kt < 4; kt++) {
            bf16x8 Bh = *(bf16x8*)&smh[(kt * 16 + lr) * CP + co];
            bf16x8 Bl = *(bf16x8*)&sml[(kt * 16 + lr) * CP + co];
            acc[kt] = __builtin_amdgcn_mfma_f32_16x16x32_bf16(Ah, Bh, acc[kt], 0, 0, 0);
            acc[kt] = __builtin_amdgcn_mfma_f32_16x16x32_bf16(Al, Bh, acc[kt], 0, 0, 0);
            acc[kt] = __builtin_amdgcn_mfma_f32_16x16x32_bf16(Ah, Bl, acc[kt], 0, 0, 0);
        }
    }

    // ---- softmax over k + cnt weighting ----
    float swv[4][4];    // [jj][kt]
    float psum[4] = {0.f, 0.f, 0.f, 0.f};
    #pragma unroll
    for (int jj = 0; jj < 4; jj++) {
        int n = n0 + wid * 16 + lg * 4 + jj;
        float v0 = acc[0][jj], v1 = acc[1][jj], v2 = acc[2][jj], v3 = acc[3][jj];
        float m = fmaxf(fmaxf(v0, v1), fmaxf(v2, v3));
        #pragma unroll
        for (int off = 1; off <= 8; off <<= 1) m = fmaxf(m, __shfl_xor(m, off));
        float e0 = __expf(v0 - m), e1 = __expf(v1 - m), e2 = __expf(v2 - m), e3 = __expf(v3 - m);
        float ss = e0 + e1 + e2 + e3;
        #pragma unroll
        for (int off = 1; off <= 8; off <<= 1) ss += __shfl_xor(ss, off);
        int y = n >> 6, xx = n & 63;
        float cnt = (float)((min(pv, y) + min(pv, 63 - y) + 1) * (min(pv, xx) + min(pv, 63 - xx) + 1));
        float sc = cnt / ss;
        swv[jj][0] = e0 * sc; swv[jj][1] = e1 * sc; swv[jj][2] = e2 * sc; swv[jj][3] = e3 * sc;
        #pragma unroll
        for (int kt = 0; kt < 4; kt++) {
            psum[kt] += swv[jj][kt];
            if (write_sig)
                sig_out[((size_t)(b * NN + n)) * K + kt * 16 + lr] = bf_hi(swv[jj][kt]);
        }
    }
    // ---- sigmaT -> LDS (hi/lo) pair-packed; psum -> redf ----
    #pragma unroll
    for (int kt = 0; kt < 4; kt++) {
        #pragma unroll
        for (int jp = 0; jp < 2; jp++) {
            float va = swv[2 * jp][kt], vb = swv[2 * jp + 1][kt];
            u16 ha = bf_hi(va), hb = bf_hi(vb);
            u16 la = bf_hi(va - bf_f(ha)), lb = bf_hi(vb - bf_f(hb));
            int col = wid * 16 + lg * 4 + 2 * jp;
            *(u32*)&sTh[(kt * 16 + lr) * SP + col] = (u32)ha | ((u32)hb << 16);
            *(u32*)&sTl[(kt * 16 + lr) * SP + col] = (u32)la | ((u32)lb << 16);
        }
        redf[(kt * 16 + lr) * 17 + wid * 4 + lg] = psum[kt];
    }
    __syncthreads();
    if (tid < 64) {
        float sd = 0.f;
        #pragma unroll
        for (int g2 = 0; g2 < 16; g2++) sd += redf[tid * 17 + g2];
        dpart[((size_t)(b * 64 + ch)) * K + tid] = sd;
    }

    // ---- M: D[k][c] = sum_n sigmaT[k][n] * x[c][n]  (B-frags direct from L2) ----
    f32x4 macc[16];
    #pragma unroll
    for (int ci = 0; ci < 16; ci++) macc[ci] = z4;
    #pragma unroll
    for (int nn2 = 0; nn2 < 2; nn2++) {
        int no = nn2 * 32 + lg * 8;
        bf16x8 Ah = *(bf16x8*)&sTh[(wid * 16 + lr) * SP + no];
        bf16x8 Al = *(bf16x8*)&sTl[(wid * 16 + lr) * SP + no];
        #pragma unroll
        for (int ci = 0; ci < 16; ci++) {
            size_t go = ((size_t)(b * C + ci * 16 + lr)) * NN + n0 + no;
            bf16x8 Bh = *(const bf16x8*)&xch[go];
            bf16x8 Bl = *(const bf16x8*)&xcl[go];
            macc[ci] = __builtin_amdgcn_mfma_f32_16x16x32_bf16(Ah, Bh, macc[ci], 0, 0, 0);
            macc[ci] = __builtin_amdgcn_mfma_f32_16x16x32_bf16(Al, Bh, macc[ci], 0, 0, 0);
            macc[ci] = __builtin_amdgcn_mfma_f32_16x16x32_bf16(Ah, Bl, macc[ci], 0, 0, 0);
        }
    }
    #pragma unroll
    for (int ci = 0; ci < 16; ci++)
        #pragma unroll
        for (int jj = 0; jj < 4; jj++)
            tpart[((size_t)((b * 64 + ch) * K + wid * 16 + lg * 4 + jj)) * C + ci * 16 + lr]
                = macc[ci][jj];
}

// ================= reduce + l2norm -> muT hi/lo + mu (into d_out) =================
// grid (K, B), block 256 (tid = c)
__global__ __launch_bounds__(256) void k_norm(
        const float* __restrict__ tpart, const float* __restrict__ dpart,
        u16* __restrict__ muth, u16* __restrict__ mutl,
        float* __restrict__ out_mu, float dconst) {
    __shared__ float red[256];
    __shared__ float dsh;
    int k = blockIdx.x, b = blockIdx.y, tid = threadIdx.x;
    float dv = 0.f;
    if (tid < 64) dv = dpart[((size_t)(b * 64 + tid)) * K + k];
    #pragma unroll
    for (int off = 1; off <= 32; off <<= 1) dv += __shfl_xor(dv, off);
    if (tid == 0) dsh = dv;
    float tt = 0.f;
    #pragma unroll 8
    for (int chn = 0; chn < 64; chn++)
        tt += tpart[((size_t)((b * 64 + chn) * K + k)) * C + tid];
    red[tid] = tt * tt;
    __syncthreads();
    for (int st = 128; st > 0; st >>= 1) {
        if (tid < st) red[tid] += red[tid + st];
        __syncthreads();
    }
    float d = dconst + dsh;
    float inv = 1.f / (1e-6f * d + sqrtf(red[0]));
    float v = tt * inv;
    u16 hh = bf_hi(v);
    size_t o = ((size_t)(b * K + k)) * C + tid;
    muth[o] = hh;
    mutl[o] = bf_hi(v - bf_f(hh));
    out_mu[((size_t)(b * C + tid)) * K + k] = v;
}

// ================= P: Pb[s][b][o][k] bf16 = sum_c w_cat[o][sC+c] mu[c][k] =================
// grid (4, B), block 256
__global__ __launch_bounds__(256) void k_pmat(
        const u16* __restrict__ wch, const u16* __restrict__ wcl,
        const u16* __restrict__ mh_g, const u16* __restrict__ ml_g,
        u16* __restrict__ Pb, int s) {
    int ob = blockIdx.x, b = blockIdx.y;
    int tid = threadIdx.x, w = tid >> 6, l = tid & 63, lg = l >> 4, lr = l & 15;
    f32x4 z4 = {0.f, 0.f, 0.f, 0.f};
    f32x4 acc[4] = {z4, z4, z4, z4};
    int orow = ob * 64 + w * 16 + lr;
    const u16* wbh = wch + (size_t)orow * W3C + s * C;
    const u16* wbl = wcl + (size_t)orow * W3C + s * C;
    for (int cc = 0; cc < 8; cc++) {
        int co = cc * 32 + lg * 8;
        bf16x8 Ah = *(const bf16x8*)&wbh[co];
        bf16x8 Al = *(const bf16x8*)&wbl[co];
        #pragma unroll
        for (int kt = 0; kt < 4; kt++) {
            bf16x8 Bh = *(const bf16x8*)&mh_g[((size_t)(b * K + kt * 16 + lr)) * C + co];
            bf16x8 Bl = *(const bf16x8*)&ml_g[((size_t)(b * K + kt * 16 + lr)) * C + co];
            acc[kt] = __builtin_amdgcn_mfma_f32_16x16x32_bf16(Ah, Bh, acc[kt], 0, 0, 0);
            acc[kt] = __builtin_amdgcn_mfma_f32_16x16x32_bf16(Al, Bh, acc[kt], 0, 0, 0);
            acc[kt] = __builtin_amdgcn_mfma_f32_16x16x32_bf16(Ah, Bl, acc[kt], 0, 0, 0);
        }
    }
    #pragma unroll
    for (int kt = 0; kt < 4; kt++)
        #pragma unroll
        for (int jj = 0; jj < 4; jj++) {
            int o = ob * 64 + w * 16 + lg * 4 + jj;
            Pb[((size_t)((s * B + b) * C + o)) * K + kt * 16 + lr] = bf_hi(acc[kt][jj]);
        }
}

// ================= final: out = relu(w*(sum_s sig_s P_s^T + b_cat) + x) =================
// grid (NN/64, C/64, B), block 256
__global__ __launch_bounds__(256) void k_final(
        const u16* __restrict__ sh_g, const u16* __restrict__ Pb,
        const float* __restrict__ x, const float* __restrict__ b_cat,
        const float* __restrict__ wscal, float* __restrict__ out) {
    __shared__ u16 ssig[64 * 72];
    __shared__ u16 sP[64 * 72];
    __shared__ float tbuf[64 * 68];
    int nt = blockIdx.x, ot = blockIdx.y, b = blockIdx.z;
    int n0 = nt * 64, o0 = ot * 64;
    int tid = threadIdx.x, w = tid >> 6, l = tid & 63, lg = l >> 4, lr = l & 15;
    f32x4 z4 = {0.f, 0.f, 0.f, 0.f};
    f32x4 acc[4] = {z4, z4, z4, z4};
    for (int s = 0; s < 3; s++) {
        __syncthreads();
        for (int t = tid; t < 512; t += 256) {
            int r = t >> 3, kc = (t & 7) * 8;
            *(u16x8*)&ssig[r * 72 + kc] =
                *(const u16x8*)&sh_g[(size_t)s * ((size_t)B * NN * K) + ((size_t)(b * NN + n0 + r)) * K + kc];
            *(u16x8*)&sP[r * 72 + kc] =
                *(const u16x8*)&Pb[((size_t)((s * B + b) * C + o0 + r)) * K + kc];
        }
        __syncthreads();
        #pragma unroll
        for (int kk = 0; kk < 2; kk++) {
            int ko = kk * 32 + lg * 8;
            bf16x8 A = *(bf16x8*)&ssig[(w * 16 + lr) * 72 + ko];
            #pragma unroll
            for (int oi = 0; oi < 4; oi++) {
                bf16x8 Bv = *(bf16x8*)&sP[(oi * 16 + lr) * 72 + ko];
                acc[oi] = __builtin_amdgcn_mfma_f32_16x16x32_bf16(A, Bv, acc[oi], 0, 0, 0);
            }
        }
    }
    __syncthreads();
    #pragma unroll
    for (int oi = 0; oi < 4; oi++)
        #pragma unroll
        for (int jj = 0; jj < 4; jj++)
            tbuf[(oi * 16 + lr) * 68 + (w * 16 + lg * 4 + jj)] = acc[oi][jj];
    __syncthreads();
    float wv = wscal[0];
    for (int t = tid; t < 1024; t += 256) {
        int ol = t >> 4, ck = (t & 15) * 4;
        int o = o0 + ol;
        float bc = b_cat[o];
        float4 u4 = *(float4*)&tbuf[ol * 68 + ck];
        size_t base = ((size_t)(b * C + o)) * NN + n0 + ck;
        float4 xv = *(const float4*)&x[base];
        float4 r;
        r.x = fmaxf((u4.x + bc) * wv + xv.x, 0.f);
        r.y = fmaxf((u4.y + bc) * wv + xv.y, 0.f);
        r.z = fmaxf((u4.z + bc) * wv + xv.z, 0.f);
        r.w = fmaxf((u4.w + bc) * wv + xv.w, 0.f);
        *(float4*)&out[base] = r;
    }
}

extern "C" void kernel_launch(void* const* d_in, const int* in_sizes, int n_in,
                              void* d_out, int out_size, void* d_ws, size_t ws_size,
                              hipStream_t stream) {
    const float* x     = (const float*)d_in[0];
    const float* mu0   = (const float*)d_in[1];
    const float* wsc   = (const float*)d_in[2];
    const float* w_cat = (const float*)d_in[3];
    const float* b_cat = (const float*)d_in[4];
    float* out = (float*)d_out;
    char* wsb = (char*)d_ws;

    const size_t SZ_XC   = (size_t)B * C * NN * 2;     // 8 MB
    const size_t SZ_MUT  = (size_t)B * K * C * 2;      // 128 KB
    const size_t SZ_SIGH = (size_t)3 * B * NN * K * 2; // 6 MB
    const size_t SZ_TP   = (size_t)B * 64 * K * C * 4; // 16 MB
    const size_t SZ_DP   = (size_t)B * 64 * K * 4;     // 64 KB
    const size_t SZ_PB   = (size_t)3 * B * C * K * 2;  // 384 KB
    const size_t SZ_WC   = (size_t)C * W3C * 2;        // 384 KB

    size_t off = 0;
    u16*   xch  = (u16*)(wsb + off); off += SZ_XC;
    u16*   xcl  = (u16*)(wsb + off); off += SZ_XC;
    u16*   muth = (u16*)(wsb + off); off += SZ_MUT;
    u16*   mutl = (u16*)(wsb + off); off += SZ_MUT;
    u16*   sigh = (u16*)(wsb + off); off += SZ_SIGH;
    float* tpart= (float*)(wsb + off); off += SZ_TP;
    float* dpart= (float*)(wsb + off); off += SZ_DP;
    u16*   Pb   = (u16*)(wsb + off); off += SZ_PB;
    u16*   wch  = (u16*)(wsb + off); off += SZ_WC;
    u16*   wcl  = (u16*)(wsb + off); off += SZ_WC;
    float* out_mu = out + (size_t)B * C * NN;

    const int EM_LDS = 4 * 64 * CP * 2 + 2 * 64 * SP * 2 + 1088 * 4;  // 157,952
    hipFuncSetAttribute((const void*)k_em, hipFuncAttributeMaxDynamicSharedMemorySize, EM_LDS);

    k_prep<<<2400, 256, 0, stream>>>(x, mu0, w_cat, xch, xcl, wch, wcl, muth, mutl);

    const int   pvals[3]   = {0, 1, 2};
    const float dconsts[3] = {1e-6f, 1e-6f + 11.9375f, 1e-6f + 59.4375f};

    for (int s = 0; s < 3; s++) {
        u16* shs = sigh + (size_t)s * ((size_t)B * NN * K);
        for (int it = 0; it < 3; it++) {
            k_em<<<dim3(64, B), 256, EM_LDS, stream>>>(xch, xcl, muth, mutl,
                                                       tpart, dpart, shs, pvals[s],
                                                       (it == 2) ? 1 : 0);
            k_norm<<<dim3(K, B), 256, 0, stream>>>(tpart, dpart, muth, mutl,
                                                   out_mu, dconsts[s]);
        }
        k_pmat<<<dim3(4, B), 256, 0, stream>>>(wch, wcl, muth, mutl, Pb, s);
    }
    k_final<<<dim3(64, 4, B), 256, 0, stream>>>(sigh, Pb, x, b_cat, wsc, out);
}

// Round 5
// 298.703 us; speedup vs baseline: 1.0587x; 1.0587x over previous
//
#include <hip/hip_runtime.h>

typedef float f32x4 __attribute__((ext_vector_type(4)));
typedef short bf16x8 __attribute__((ext_vector_type(8)));
typedef unsigned short u16;
typedef u16 u16x8 __attribute__((ext_vector_type(8)));
typedef unsigned int u32;

#define B 4
#define C 256
#define K 64
#define NN 4096
#define W3C 768
#define CP 264   // padded LDS row (shorts) for 256-col muT tile
#define SP 72    // padded LDS row (shorts) for 64-col sigmaT tile

__device__ __forceinline__ u16 bf_hi(float f) {
    unsigned u = __float_as_uint(f);
    u += 0x7FFFu + ((u >> 16) & 1u);
    return (u16)(u >> 16);
}
__device__ __forceinline__ float bf_f(u16 s) { return __uint_as_float(((unsigned)s) << 16); }

// ================= prep A: x->hi/lo (c-major), w_cat->hi/lo, mu init =================
__global__ void k_prep(const float* __restrict__ x, const float* __restrict__ mu0,
                       const float* __restrict__ w_cat,
                       u16* __restrict__ xch, u16* __restrict__ xcl,
                       u16* __restrict__ wch, u16* __restrict__ wcl,
                       u16* __restrict__ muth, u16* __restrict__ mutl) {
    int blk = blockIdx.x, tid = threadIdx.x;
    if (blk < 2048) {
        int i = blk * 256 + tid;
        const float4* s4 = (const float4*)(x + (size_t)i * 8);
        float4 a = s4[0], bq = s4[1];
        float v[8] = {a.x, a.y, a.z, a.w, bq.x, bq.y, bq.z, bq.w};
        u16x8 hv, lv;
        #pragma unroll
        for (int j = 0; j < 8; j++) { u16 hh = bf_hi(v[j]); hv[j] = hh; lv[j] = bf_hi(v[j] - bf_f(hh)); }
        *(u16x8*)(xch + (size_t)i * 8) = hv;
        *(u16x8*)(xcl + (size_t)i * 8) = lv;
    } else if (blk < 2144) {
        int i = (blk - 2048) * 256 + tid;
        const float4* s4 = (const float4*)(w_cat + (size_t)i * 8);
        float4 a = s4[0], bq = s4[1];
        float v[8] = {a.x, a.y, a.z, a.w, bq.x, bq.y, bq.z, bq.w};
        u16x8 hv, lv;
        #pragma unroll
        for (int j = 0; j < 8; j++) { u16 hh = bf_hi(v[j]); hv[j] = hh; lv[j] = bf_hi(v[j] - bf_f(hh)); }
        *(u16x8*)(wch + (size_t)i * 8) = hv;
        *(u16x8*)(wcl + (size_t)i * 8) = lv;
    } else {
        int g = (blk - 2144) * 256 + tid;   // (b*K+k)*C+c
        int kq = (g >> 8) & 63, cq = g & 255;
        float v = mu0[cq * K + kq];
        u16 hh = bf_hi(v);
        muth[g] = hh;
        mutl[g] = bf_hi(v - bf_f(hh));
    }
}

// ================= prep B: transpose x -> xT (b,n,c) bf16 hi/lo (coalesced) =================
__global__ void k_prept(const float* __restrict__ x, u16* __restrict__ th,
                        u16* __restrict__ tl) {
    __shared__ float tile[32][33];
    int b = blockIdx.z, c0 = blockIdx.y * 32, n0 = blockIdx.x * 32;
    int tx = threadIdx.x, ty = threadIdx.y;
    #pragma unroll
    for (int j = 0; j < 4; j++)
        tile[ty + j * 8][tx] = x[((size_t)(b * C + c0 + ty + j * 8)) * NN + n0 + tx];
    __syncthreads();
    #pragma unroll
    for (int j = 0; j < 4; j++) {
        int n = n0 + ty + j * 8;
        float v = tile[tx][ty + j * 8];
        u16 hh = bf_hi(v);
        size_t o = ((size_t)(b * NN + n)) * C + c0 + tx;
        th[o] = hh;
        tl[o] = bf_hi(v - bf_f(hh));
    }
}

// ================= fused E+M step (low-LDS, direct-global fragments) =================
// grid (64, B), block 256, dynamic LDS 90,368 B
__global__ __launch_bounds__(256) void k_em(
        const u16* __restrict__ xth, const u16* __restrict__ xtl,
        const u16* __restrict__ xch, const u16* __restrict__ xcl,
        const u16* __restrict__ muth, const u16* __restrict__ mutl,
        float* __restrict__ tpart, float* __restrict__ dpart,
        u16* __restrict__ sig_out, int pv, int write_sig)
{
    extern __shared__ char smem[];
    u16* smh = (u16*)smem;            // [64][CP] muT hi: rows k, cols c
    u16* sml = smh + 64 * CP;
    u16* sTh = sml + 64 * CP;         // [64][SP] sigmaT hi: rows k, cols n_local
    u16* sTl = sTh + 64 * SP;
    float* redf = (float*)(sTl + 64 * SP);  // 1088 floats

    const int ch = blockIdx.x, b = blockIdx.y, tid = threadIdx.x;
    const int n0 = ch * 64;

    // ---- stage muT [64k][256c] hi/lo (coalesced) ----
    {
        size_t mbase = ((size_t)(b * K)) * C;
        for (int t = tid; t < 2048; t += 256) {
            int r = t >> 5, cof = (t & 31) * 8;
            *(u16x8*)&smh[r * CP + cof] = *(const u16x8*)&muth[mbase + (size_t)r * C + cof];
            *(u16x8*)&sml[r * CP + cof] = *(const u16x8*)&mutl[mbase + (size_t)r * C + cof];
        }
    }
    __syncthreads();

    const int wid = tid >> 6, l = tid & 63, lg = l >> 4, lr = l & 15;
    f32x4 z4 = {0.f, 0.f, 0.f, 0.f};

    // ---- E: logits[n][k] = sum_c x[n][c]*mu[k][c]; A-frags DIRECT from global xT ----
    f32x4 acc[4] = {z4, z4, z4, z4};
    {
        const u16* xrh = xth + ((size_t)(b * NN + n0 + wid * 16 + lr)) * C;
        const u16* xrl = xtl + ((size_t)(b * NN + n0 + wid * 16 + lr)) * C;
        for (int cc = 0; cc < 8; cc++) {
            int co = cc * 32 + lg * 8;
            bf16x8 Ah = *(const bf16x8*)&xrh[co];
            bf16x8 Al = *(const bf16x8*)&xrl[co];
            #pragma unroll
            for (int kt = 0; kt < 4; kt++) {
                bf16x8 Bh = *(bf16x8*)&smh[(kt * 16 + lr) * CP + co];
                bf16x8 Bl = *(bf16x8*)&sml[(kt * 16 + lr) * CP + co];
                acc[kt] = __builtin_amdgcn_mfma_f32_16x16x32_bf16(Ah, Bh, acc[kt], 0, 0, 0);
                acc[kt] = __builtin_amdgcn_mfma_f32_16x16x32_bf16(Al, Bh, acc[kt], 0, 0, 0);
                acc[kt] = __builtin_amdgcn_mfma_f32_16x16x32_bf16(Ah, Bl, acc[kt], 0, 0, 0);
            }
        }
    }

    // ---- softmax over k + cnt weighting ----
    float swv[4][4];
    float psum[4] = {0.f, 0.f, 0.f, 0.f};
    #pragma unroll
    for (int jj = 0; jj < 4; jj++) {
        int n = n0 + wid * 16 + lg * 4 + jj;
        float v0 = acc[0][jj], v1 = acc[1][jj], v2 = acc[2][jj], v3 = acc[3][jj];
        float m = fmaxf(fmaxf(v0, v1), fmaxf(v2, v3));
        #pragma unroll
        for (int off = 1; off <= 8; off <<= 1) m = fmaxf(m, __shfl_xor(m, off));
        float e0 = __expf(v0 - m), e1 = __expf(v1 - m), e2 = __expf(v2 - m), e3 = __expf(v3 - m);
        float ss = e0 + e1 + e2 + e3;
        #pragma unroll
        for (int off = 1; off <= 8; off <<= 1) ss += __shfl_xor(ss, off);
        int y = n >> 6, xx = n & 63;
        float cnt = (float)((min(pv, y) + min(pv, 63 - y) + 1) * (min(pv, xx) + min(pv, 63 - xx) + 1));
        float sc = cnt / ss;
        swv[jj][0] = e0 * sc; swv[jj][1] = e1 * sc; swv[jj][2] = e2 * sc; swv[jj][3] = e3 * sc;
        #pragma unroll
        for (int kt = 0; kt < 4; kt++) {
            psum[kt] += swv[jj][kt];
            if (write_sig)
                sig_out[((size_t)(b * NN + n)) * K + kt * 16 + lr] = bf_hi(swv[jj][kt]);
        }
    }
    // ---- sigmaT -> LDS (hi/lo) pair-packed; psum -> redf ----
    #pragma unroll
    for (int kt = 0; kt < 4; kt++) {
        #pragma unroll
        for (int jp = 0; jp < 2; jp++) {
            float va = swv[2 * jp][kt], vb = swv[2 * jp + 1][kt];
            u16 ha = bf_hi(va), hb = bf_hi(vb);
            u16 la = bf_hi(va - bf_f(ha)), lb = bf_hi(vb - bf_f(hb));
            int col = wid * 16 + lg * 4 + 2 * jp;
            *(u32*)&sTh[(kt * 16 + lr) * SP + col] = (u32)ha | ((u32)hb << 16);
            *(u32*)&sTl[(kt * 16 + lr) * SP + col] = (u32)la | ((u32)lb << 16);
        }
        redf[(kt * 16 + lr) * 17 + wid * 4 + lg] = psum[kt];
    }
    __syncthreads();
    if (tid < 64) {
        float sd = 0.f;
        #pragma unroll
        for (int g2 = 0; g2 < 16; g2++) sd += redf[tid * 17 + g2];
        dpart[((size_t)(b * 64 + ch)) * K + tid] = sd;
    }

    // ---- M: D[k][c] = sum_n sigmaT[k][n]*x[c][n]; B-frags DIRECT from global (line-exact) ----
    f32x4 macc[16];
    #pragma unroll
    for (int ci = 0; ci < 16; ci++) macc[ci] = z4;
    #pragma unroll
    for (int nn2 = 0; nn2 < 2; nn2++) {
        int no = nn2 * 32 + lg * 8;
        bf16x8 Ah = *(bf16x8*)&sTh[(wid * 16 + lr) * SP + no];
        bf16x8 Al = *(bf16x8*)&sTl[(wid * 16 + lr) * SP + no];
        #pragma unroll
        for (int ci = 0; ci < 16; ci++) {
            size_t go = ((size_t)(b * C + ci * 16 + lr)) * NN + n0 + no;
            bf16x8 Bh = *(const bf16x8*)&xch[go];
            bf16x8 Bl = *(const bf16x8*)&xcl[go];
            macc[ci] = __builtin_amdgcn_mfma_f32_16x16x32_bf16(Ah, Bh, macc[ci], 0, 0, 0);
            macc[ci] = __builtin_amdgcn_mfma_f32_16x16x32_bf16(Al, Bh, macc[ci], 0, 0, 0);
            macc[ci] = __builtin_amdgcn_mfma_f32_16x16x32_bf16(Ah, Bl, macc[ci], 0, 0, 0);
        }
    }
    #pragma unroll
    for (int ci = 0; ci < 16; ci++)
        #pragma unroll
        for (int jj = 0; jj < 4; jj++)
            tpart[((size_t)((b * 64 + ch) * K + wid * 16 + lg * 4 + jj)) * C + ci * 16 + lr]
                = macc[ci][jj];
}

// ================= reduce + l2norm -> muT hi/lo + mu (into d_out) =================
// grid (K, B), block 256 (tid = c)
__global__ __launch_bounds__(256) void k_norm(
        const float* __restrict__ tpart, const float* __restrict__ dpart,
        u16* __restrict__ muth, u16* __restrict__ mutl,
        float* __restrict__ out_mu, float dconst) {
    __shared__ float red[256];
    __shared__ float dsh;
    int k = blockIdx.x, b = blockIdx.y, tid = threadIdx.x;
    float dv = 0.f;
    if (tid < 64) dv = dpart[((size_t)(b * 64 + tid)) * K + k];
    #pragma unroll
    for (int off = 1; off <= 32; off <<= 1) dv += __shfl_xor(dv, off);
    if (tid == 0) dsh = dv;
    float tt = 0.f;
    #pragma unroll 8
    for (int chn = 0; chn < 64; chn++)
        tt += tpart[((size_t)((b * 64 + chn) * K + k)) * C + tid];
    red[tid] = tt * tt;
    __syncthreads();
    for (int st = 128; st > 0; st >>= 1) {
        if (tid < st) red[tid] += red[tid + st];
        __syncthreads();
    }
    float d = dconst + dsh;
    float inv = 1.f / (1e-6f * d + sqrtf(red[0]));
    float v = tt * inv;
    u16 hh = bf_hi(v);
    size_t o = ((size_t)(b * K + k)) * C + tid;
    muth[o] = hh;
    mutl[o] = bf_hi(v - bf_f(hh));
    out_mu[((size_t)(b * C + tid)) * K + k] = v;
}

// ================= P: Pb[s][b][o][k] bf16 = sum_c w_cat[o][sC+c] mu[c][k] =================
// grid (4, B), block 256
__global__ __launch_bounds__(256) void k_pmat(
        const u16* __restrict__ wch, const u16* __restrict__ wcl,
        const u16* __restrict__ mh_g, const u16* __restrict__ ml_g,
        u16* __restrict__ Pb, int s) {
    int ob = blockIdx.x, b = blockIdx.y;
    int tid = threadIdx.x, w = tid >> 6, l = tid & 63, lg = l >> 4, lr = l & 15;
    f32x4 z4 = {0.f, 0.f, 0.f, 0.f};
    f32x4 acc[4] = {z4, z4, z4, z4};
    int orow = ob * 64 + w * 16 + lr;
    const u16* wbh = wch + (size_t)orow * W3C + s * C;
    const u16* wbl = wcl + (size_t)orow * W3C + s * C;
    for (int cc = 0; cc < 8; cc++) {
        int co = cc * 32 + lg * 8;
        bf16x8 Ah = *(const bf16x8*)&wbh[co];
        bf16x8 Al = *(const bf16x8*)&wbl[co];
        #pragma unroll
        for (int kt = 0; kt < 4; kt++) {
            bf16x8 Bh = *(const bf16x8*)&mh_g[((size_t)(b * K + kt * 16 + lr)) * C + co];
            bf16x8 Bl = *(const bf16x8*)&ml_g[((size_t)(b * K + kt * 16 + lr)) * C + co];
            acc[kt] = __builtin_amdgcn_mfma_f32_16x16x32_bf16(Ah, Bh, acc[kt], 0, 0, 0);
            acc[kt] = __builtin_amdgcn_mfma_f32_16x16x32_bf16(Al, Bh, acc[kt], 0, 0, 0);
            acc[kt] = __builtin_amdgcn_mfma_f32_16x16x32_bf16(Ah, Bl, acc[kt], 0, 0, 0);
        }
    }
    #pragma unroll
    for (int kt = 0; kt < 4; kt++)
        #pragma unroll
        for (int jj = 0; jj < 4; jj++) {
            int o = ob * 64 + w * 16 + lg * 4 + jj;
            Pb[((size_t)((s * B + b) * C + o)) * K + kt * 16 + lr] = bf_hi(acc[kt][jj]);
        }
}

// ================= final: out = relu(w*(sum_s sig_s P_s^T + b_cat) + x) =================
// grid (NN/64, C/64, B), block 256
__global__ __launch_bounds__(256) void k_final(
        const u16* __restrict__ sh_g, const u16* __restrict__ Pb,
        const float* __restrict__ x, const float* __restrict__ b_cat,
        const float* __restrict__ wscal, float* __restrict__ out) {
    __shared__ u16 ssig[64 * 72];
    __shared__ u16 sP[64 * 72];
    __shared__ float tbuf[64 * 68];
    int nt = blockIdx.x, ot = blockIdx.y, b = blockIdx.z;
    int n0 = nt * 64, o0 = ot * 64;
    int tid = threadIdx.x, w = tid >> 6, l = tid & 63, lg = l >> 4, lr = l & 15;
    f32x4 z4 = {0.f, 0.f, 0.f, 0.f};
    f32x4 acc[4] = {z4, z4, z4, z4};
    for (int s = 0; s < 3; s++) {
        __syncthreads();
        for (int t = tid; t < 512; t += 256) {
            int r = t >> 3, kc = (t & 7) * 8;
            *(u16x8*)&ssig[r * 72 + kc] =
                *(const u16x8*)&sh_g[(size_t)s * ((size_t)B * NN * K) + ((size_t)(b * NN + n0 + r)) * K + kc];
            *(u16x8*)&sP[r * 72 + kc] =
                *(const u16x8*)&Pb[((size_t)((s * B + b) * C + o0 + r)) * K + kc];
        }
        __syncthreads();
        #pragma unroll
        for (int kk = 0; kk < 2; kk++) {
            int ko = kk * 32 + lg * 8;
            bf16x8 A = *(bf16x8*)&ssig[(w * 16 + lr) * 72 + ko];
            #pragma unroll
            for (int oi = 0; oi < 4; oi++) {
                bf16x8 Bv = *(bf16x8*)&sP[(oi * 16 + lr) * 72 + ko];
                acc[oi] = __builtin_amdgcn_mfma_f32_16x16x32_bf16(A, Bv, acc[oi], 0, 0, 0);
            }
        }
    }
    __syncthreads();
    #pragma unroll
    for (int oi = 0; oi < 4; oi++)
        #pragma unroll
        for (int jj = 0; jj < 4; jj++)
            tbuf[(oi * 16 + lr) * 68 + (w * 16 + lg * 4 + jj)] = acc[oi][jj];
    __syncthreads();
    float wv = wscal[0];
    for (int t = tid; t < 1024; t += 256) {
        int ol = t >> 4, ck = (t & 15) * 4;
        int o = o0 + ol;
        float bc = b_cat[o];
        float4 u4 = *(float4*)&tbuf[ol * 68 + ck];
        size_t base = ((size_t)(b * C + o)) * NN + n0 + ck;
        float4 xv = *(const float4*)&x[base];
        float4 r;
        r.x = fmaxf((u4.x + bc) * wv + xv.x, 0.f);
        r.y = fmaxf((u4.y + bc) * wv + xv.y, 0.f);
        r.z = fmaxf((u4.z + bc) * wv + xv.z, 0.f);
        r.w = fmaxf((u4.w + bc) * wv + xv.w, 0.f);
        *(float4*)&out[base] = r;
    }
}

extern "C" void kernel_launch(void* const* d_in, const int* in_sizes, int n_in,
                              void* d_out, int out_size, void* d_ws, size_t ws_size,
                              hipStream_t stream) {
    const float* x     = (const float*)d_in[0];
    const float* mu0   = (const float*)d_in[1];
    const float* wsc   = (const float*)d_in[2];
    const float* w_cat = (const float*)d_in[3];
    const float* b_cat = (const float*)d_in[4];
    float* out = (float*)d_out;
    char* wsb = (char*)d_ws;

    const size_t SZ_X2   = (size_t)B * C * NN * 2;     // 8 MB (one hi or lo array)
    const size_t SZ_MUT  = (size_t)B * K * C * 2;      // 128 KB
    const size_t SZ_SIGH = (size_t)3 * B * NN * K * 2; // 6 MB
    const size_t SZ_TP   = (size_t)B * 64 * K * C * 4; // 16 MB
    const size_t SZ_DP   = (size_t)B * 64 * K * 4;     // 64 KB
    const size_t SZ_PB   = (size_t)3 * B * C * K * 2;  // 384 KB
    const size_t SZ_WC   = (size_t)C * W3C * 2;        // 384 KB

    size_t off = 0;
    u16*   xch  = (u16*)(wsb + off); off += SZ_X2;
    u16*   xcl  = (u16*)(wsb + off); off += SZ_X2;
    u16*   xth  = (u16*)(wsb + off); off += SZ_X2;
    u16*   xtl  = (u16*)(wsb + off); off += SZ_X2;
    u16*   muth = (u16*)(wsb + off); off += SZ_MUT;
    u16*   mutl = (u16*)(wsb + off); off += SZ_MUT;
    u16*   sigh = (u16*)(wsb + off); off += SZ_SIGH;
    float* tpart= (float*)(wsb + off); off += SZ_TP;
    float* dpart= (float*)(wsb + off); off += SZ_DP;
    u16*   Pb   = (u16*)(wsb + off); off += SZ_PB;
    u16*   wch  = (u16*)(wsb + off); off += SZ_WC;
    u16*   wcl  = (u16*)(wsb + off); off += SZ_WC;
    float* out_mu = out + (size_t)B * C * NN;

    const int EM_LDS = 2 * 64 * CP * 2 + 2 * 64 * SP * 2 + 1088 * 4;  // 90,368
    hipFuncSetAttribute((const void*)k_em, hipFuncAttributeMaxDynamicSharedMemorySize, EM_LDS);

    k_prep<<<2400, 256, 0, stream>>>(x, mu0, w_cat, xch, xcl, wch, wcl, muth, mutl);
    k_prept<<<dim3(128, 8, B), dim3(32, 8), 0, stream>>>(x, xth, xtl);

    const int   pvals[3]   = {0, 1, 2};
    const float dconsts[3] = {1e-6f, 1e-6f + 11.9375f, 1e-6f + 59.4375f};

    for (int s = 0; s < 3; s++) {
        u16* shs = sigh + (size_t)s * ((size_t)B * NN * K);
        for (int it = 0; it < 3; it++) {
            k_em<<<dim3(64, B), 256, EM_LDS, stream>>>(xth, xtl, xch, xcl, muth, mutl,
                                                       tpart, dpart, shs, pvals[s],
                                                       (it == 2) ? 1 : 0);
            k_norm<<<dim3(K, B), 256, 0, stream>>>(tpart, dpart, muth, mutl,
                                                   out_mu, dconsts[s]);
        }
        k_pmat<<<dim3(4, B), 256, 0, stream>>>(wch, wcl, muth, mutl, Pb, s);
    }
    k_final<<<dim3(64, 4, B), 256, 0, stream>>>(sigh, Pb, x, b_cat, wsc, out);
}

// Round 6
// 290.724 us; speedup vs baseline: 1.0878x; 1.0274x over previous
//
#include <hip/hip_runtime.h>

typedef float f32x4 __attribute__((ext_vector_type(4)));
typedef short bf16x8 __attribute__((ext_vector_type(8)));
typedef unsigned short u16;
typedef u16 u16x8 __attribute__((ext_vector_type(8)));
typedef unsigned int u32;

#define B 4
#define C 256
#define K 64
#define NN 4096
#define W3C 768
#define CP 264   // muT LDS pitch (shorts)
#define SP 72    // sigmaT LDS pitch (shorts)
#define LGP 68   // logits LDS pitch (floats)

__device__ __forceinline__ u16 bf_hi(float f) {
    unsigned u = __float_as_uint(f);
    u += 0x7FFFu + ((u >> 16) & 1u);
    return (u16)(u >> 16);
}
__device__ __forceinline__ float bf_f(u16 s) { return __uint_as_float(((unsigned)s) << 16); }

// ================= prep: x->hi/lo, w_cat->hi/lo, mu0 pack, zero tpart buf0 =================
// grid 2464 x 256
__global__ void k_prep(const float* __restrict__ x, const float* __restrict__ mu0,
                       const float* __restrict__ w_cat,
                       u16* __restrict__ xch, u16* __restrict__ xcl,
                       u16* __restrict__ wch, u16* __restrict__ wcl,
                       u16* __restrict__ muth, u16* __restrict__ mutl,
                       float* __restrict__ tp0) {
    int blk = blockIdx.x, tid = threadIdx.x;
    if (blk < 2048) {
        int i = blk * 256 + tid;
        const float4* s4 = (const float4*)(x + (size_t)i * 8);
        float4 a = s4[0], bq = s4[1];
        float v[8] = {a.x, a.y, a.z, a.w, bq.x, bq.y, bq.z, bq.w};
        u16x8 hv, lv;
        #pragma unroll
        for (int j = 0; j < 8; j++) { u16 hh = bf_hi(v[j]); hv[j] = hh; lv[j] = bf_hi(v[j] - bf_f(hh)); }
        *(u16x8*)(xch + (size_t)i * 8) = hv;
        *(u16x8*)(xcl + (size_t)i * 8) = lv;
    } else if (blk < 2144) {
        int i = (blk - 2048) * 256 + tid;
        const float4* s4 = (const float4*)(w_cat + (size_t)i * 8);
        float4 a = s4[0], bq = s4[1];
        float v[8] = {a.x, a.y, a.z, a.w, bq.x, bq.y, bq.z, bq.w};
        u16x8 hv, lv;
        #pragma unroll
        for (int j = 0; j < 8; j++) { u16 hh = bf_hi(v[j]); hv[j] = hh; lv[j] = bf_hi(v[j] - bf_f(hh)); }
        *(u16x8*)(wch + (size_t)i * 8) = hv;
        *(u16x8*)(wcl + (size_t)i * 8) = lv;
    } else if (blk < 2400) {
        int g = (blk - 2144) * 256 + tid;   // (b*K+k)*C+c
        int kq = (g >> 8) & 63, cq = g & 255;
        float v = mu0[cq * K + kq];
        u16 hh = bf_hi(v);
        muth[g] = hh;
        mutl[g] = bf_hi(v - bf_f(hh));
    } else {
        int i = (blk - 2400) * 256 + tid;   // 65536 float4-groups? 64 blk*256 thr = 16384 -> 4 f32 each
        float4 z = {0.f, 0.f, 0.f, 0.f};
        *(float4*)&tp0[(size_t)i * 4] = z;
    }
}

// ================= transpose x -> xT (b,n,c) bf16 hi/lo =================
__global__ void k_prept(const float* __restrict__ x, u16* __restrict__ th,
                        u16* __restrict__ tl) {
    __shared__ float tile[32][33];
    int b = blockIdx.z, c0 = blockIdx.y * 32, n0 = blockIdx.x * 32;
    int tx = threadIdx.x, ty = threadIdx.y;
    #pragma unroll
    for (int j = 0; j < 4; j++)
        tile[ty + j * 8][tx] = x[((size_t)(b * C + c0 + ty + j * 8)) * NN + n0 + tx];
    __syncthreads();
    #pragma unroll
    for (int j = 0; j < 4; j++) {
        int n = n0 + ty + j * 8;
        float v = tile[tx][ty + j * 8];
        u16 hh = bf_hi(v);
        size_t o = ((size_t)(b * NN + n)) * C + c0 + tx;
        th[o] = hh;
        tl[o] = bf_hi(v - bf_f(hh));
    }
}

// ================= fused norm-prologue + E + M (+pmat) =================
// grid (64, B), block 512, dynamic LDS 108,032 B
__global__ __launch_bounds__(512) void k_em(
        const u16* __restrict__ xth, const u16* __restrict__ xtl,
        const u16* __restrict__ xch, const u16* __restrict__ xcl,
        const u16* __restrict__ muth, const u16* __restrict__ mutl,
        const float* __restrict__ tp_prev, float* __restrict__ tp_cur,
        float* __restrict__ tp_next, float* __restrict__ dpart,
        u16* __restrict__ sig_out, u16* __restrict__ Pb,
        const u16* __restrict__ wch, const u16* __restrict__ wcl,
        int iter, int pv, float dconst_prev, int write_sig, int s_prev)
{
    extern __shared__ char smem[];
    u16* smh   = (u16*)smem;                   // muT hi [64][CP]
    u16* sml   = smh + 64 * CP;                // muT lo
    float* slog = (float*)(sml + 64 * CP);     // partial logits [64][LGP]
    u16* sTh   = (u16*)(slog + 64 * LGP);      // sigmaT hi [64][SP]
    u16* sTl   = sTh + 64 * SP;                // sigmaT lo
    float* redf = (float*)(sTl + 64 * SP);     // 1152 floats scratch

    const int ch = blockIdx.x, b = blockIdx.y, tid = threadIdx.x;
    const int n0 = ch * 64;
    const int w = tid >> 6, l = tid & 63, lg = l >> 4, lr = l & 15;
    f32x4 z4 = {0.f, 0.f, 0.f, 0.f};

    // zero this block's slice of the NEXT tpart buffer (no one touches it this iter)
    if (tid < 256) tp_next[(size_t)b * K * C + ch * 256 + tid] = 0.f;

    float vals[32];
    float inv = 0.f;
    int kq = tid >> 3, g = tid & 7;
    if (iter == 0) {
        size_t mbase = (size_t)(b * K) * C;
        for (int t = tid; t < 2048; t += 512) {
            int r = t >> 5, cof = (t & 31) * 8;
            *(u16x8*)&smh[r * CP + cof] = *(const u16x8*)&muth[mbase + (size_t)r * C + cof];
            *(u16x8*)&sml[r * CP + cof] = *(const u16x8*)&mutl[mbase + (size_t)r * C + cof];
        }
    } else {
        if (tid < 64) {
            float dv = 0.f;
            #pragma unroll 8
            for (int c2 = 0; c2 < 64; c2++) dv += dpart[((size_t)(b * 64 + c2)) * K + tid];
            redf[1088 + tid] = dv;
        }
        // thread (k=kq, g) reduces+normalizes cols g*32..g*32+31 of row k
        const float* tp = tp_prev + (size_t)b * K * C + (size_t)kq * C + g * 32;
        float ssq = 0.f;
        #pragma unroll
        for (int j4 = 0; j4 < 8; j4++) {
            float4 v4 = *(const float4*)&tp[j4 * 4];
            vals[j4 * 4 + 0] = v4.x; vals[j4 * 4 + 1] = v4.y;
            vals[j4 * 4 + 2] = v4.z; vals[j4 * 4 + 3] = v4.w;
            ssq += v4.x * v4.x + v4.y * v4.y + v4.z * v4.z + v4.w * v4.w;
        }
        #pragma unroll
        for (int off = 1; off <= 4; off <<= 1) ssq += __shfl_xor(ssq, off);
        __syncthreads();   // redf d-values ready (uniform branch: iter is grid-uniform)
        float d = dconst_prev + redf[1088 + kq];
        inv = 1.f / (1e-6f * d + sqrtf(ssq));
        // pack normalized row into muT LDS
        #pragma unroll
        for (int j8 = 0; j8 < 4; j8++) {
            u16x8 hv, lv;
            #pragma unroll
            for (int j = 0; j < 8; j++) {
                float v = vals[j8 * 8 + j] * inv;
                u16 hh = bf_hi(v);
                hv[j] = hh; lv[j] = bf_hi(v - bf_f(hh));
            }
            *(u16x8*)&smh[kq * CP + g * 32 + j8 * 8] = hv;
            *(u16x8*)&sml[kq * CP + g * 32 + j8 * 8] = lv;
        }
    }
    __syncthreads();   // muT ready

    // ---- folded P-matrix for the just-finished scale (16 blocks only) ----
    if (s_prev >= 0 && ch < 4) {
        f32x4 pacc[2] = {z4, z4};
        int orow = ch * 64 + (w & 3) * 16 + lr;
        const u16* wbh = wch + (size_t)orow * W3C + s_prev * C;
        const u16* wbl = wcl + (size_t)orow * W3C + s_prev * C;
        for (int cc = 0; cc < 8; cc++) {
            int co = cc * 32 + lg * 8;
            bf16x8 Ah = *(const bf16x8*)&wbh[co];
            bf16x8 Al = *(const bf16x8*)&wbl[co];
            #pragma unroll
            for (int ktl = 0; ktl < 2; ktl++) {
                int kt = (w >> 2) * 2 + ktl;
                bf16x8 Bh = *(bf16x8*)&smh[(kt * 16 + lr) * CP + co];
                bf16x8 Bl = *(bf16x8*)&sml[(kt * 16 + lr) * CP + co];
                pacc[ktl] = __builtin_amdgcn_mfma_f32_16x16x32_bf16(Ah, Bh, pacc[ktl], 0, 0, 0);
                pacc[ktl] = __builtin_amdgcn_mfma_f32_16x16x32_bf16(Al, Bh, pacc[ktl], 0, 0, 0);
                pacc[ktl] = __builtin_amdgcn_mfma_f32_16x16x32_bf16(Ah, Bl, pacc[ktl], 0, 0, 0);
            }
        }
        #pragma unroll
        for (int ktl = 0; ktl < 2; ktl++)
            #pragma unroll
            for (int jj = 0; jj < 4; jj++) {
                int o = ch * 64 + (w & 3) * 16 + lg * 4 + jj;
                int kk = ((w >> 2) * 2 + ktl) * 16 + lr;
                Pb[((size_t)((s_prev * B + b) * C + o)) * K + kk] = bf_hi(pacc[ktl][jj]);
            }
    }

    // ---- E: partial logits, c-split across wave halves ----
    f32x4 acc[4] = {z4, z4, z4, z4};
    {
        int chalf = (w >> 2) * 128;
        const u16* xrh = xth + ((size_t)(b * NN + n0 + (w & 3) * 16 + lr)) * C + chalf;
        const u16* xrl = xtl + ((size_t)(b * NN + n0 + (w & 3) * 16 + lr)) * C + chalf;
        for (int cc = 0; cc < 4; cc++) {
            int co = cc * 32 + lg * 8;
            bf16x8 Ah = *(const bf16x8*)&xrh[co];
            bf16x8 Al = *(const bf16x8*)&xrl[co];
            #pragma unroll
            for (int kt = 0; kt < 4; kt++) {
                bf16x8 Bh = *(bf16x8*)&smh[(kt * 16 + lr) * CP + chalf + co];
                bf16x8 Bl = *(bf16x8*)&sml[(kt * 16 + lr) * CP + chalf + co];
                acc[kt] = __builtin_amdgcn_mfma_f32_16x16x32_bf16(Ah, Bh, acc[kt], 0, 0, 0);
                acc[kt] = __builtin_amdgcn_mfma_f32_16x16x32_bf16(Al, Bh, acc[kt], 0, 0, 0);
                acc[kt] = __builtin_amdgcn_mfma_f32_16x16x32_bf16(Ah, Bl, acc[kt], 0, 0, 0);
            }
        }
    }
    if (w < 4) {
        #pragma unroll
        for (int kt = 0; kt < 4; kt++)
            #pragma unroll
            for (int jj = 0; jj < 4; jj++)
                slog[((w & 3) * 16 + lg * 4 + jj) * LGP + kt * 16 + lr] = acc[kt][jj];
    }
    __syncthreads();

    // ---- softmax + cnt weight + sigmaT pack (waves 4-7) ----
    if (w >= 4) {
        float swv[4][4];
        float psum[4] = {0.f, 0.f, 0.f, 0.f};
        #pragma unroll
        for (int jj = 0; jj < 4; jj++) {
            int rloc = (w & 3) * 16 + lg * 4 + jj;
            int n = n0 + rloc;
            float v0 = acc[0][jj] + slog[rloc * LGP + 0 * 16 + lr];
            float v1 = acc[1][jj] + slog[rloc * LGP + 1 * 16 + lr];
            float v2 = acc[2][jj] + slog[rloc * LGP + 2 * 16 + lr];
            float v3 = acc[3][jj] + slog[rloc * LGP + 3 * 16 + lr];
            float m = fmaxf(fmaxf(v0, v1), fmaxf(v2, v3));
            #pragma unroll
            for (int off = 1; off <= 8; off <<= 1) m = fmaxf(m, __shfl_xor(m, off));
            float e0 = __expf(v0 - m), e1 = __expf(v1 - m), e2 = __expf(v2 - m), e3 = __expf(v3 - m);
            float ss = e0 + e1 + e2 + e3;
            #pragma unroll
            for (int off = 1; off <= 8; off <<= 1) ss += __shfl_xor(ss, off);
            int y = n >> 6, xx = n & 63;
            float cnt = (float)((min(pv, y) + min(pv, 63 - y) + 1) * (min(pv, xx) + min(pv, 63 - xx) + 1));
            float sc = cnt / ss;
            swv[jj][0] = e0 * sc; swv[jj][1] = e1 * sc; swv[jj][2] = e2 * sc; swv[jj][3] = e3 * sc;
            #pragma unroll
            for (int kt = 0; kt < 4; kt++) {
                psum[kt] += swv[jj][kt];
                if (write_sig)
                    sig_out[((size_t)(b * NN + n)) * K + kt * 16 + lr] = bf_hi(swv[jj][kt]);
            }
        }
        #pragma unroll
        for (int kt = 0; kt < 4; kt++) {
            #pragma unroll
            for (int jp = 0; jp < 2; jp++) {
                float va = swv[2 * jp][kt], vb = swv[2 * jp + 1][kt];
                u16 ha = bf_hi(va), hb = bf_hi(vb);
                u16 la = bf_hi(va - bf_f(ha)), lb = bf_hi(vb - bf_f(hb));
                int col = (w & 3) * 16 + lg * 4 + 2 * jp;
                *(u32*)&sTh[(kt * 16 + lr) * SP + col] = (u32)ha | ((u32)hb << 16);
                *(u32*)&sTl[(kt * 16 + lr) * SP + col] = (u32)la | ((u32)lb << 16);
            }
            redf[(kt * 16 + lr) * 17 + (w & 3) * 4 + lg] = psum[kt];
        }
    }
    __syncthreads();
    if (tid < 64) {
        float sd = 0.f;
        #pragma unroll
        for (int g2 = 0; g2 < 16; g2++) sd += redf[tid * 17 + g2];
        dpart[((size_t)(b * 64 + ch)) * K + tid] = sd;
    }

    // ---- M: D[k][c] partials, ci split 8 ways, atomic accumulate ----
    f32x4 macc[8];
    #pragma unroll
    for (int t = 0; t < 8; t++) macc[t] = z4;
    #pragma unroll
    for (int nn2 = 0; nn2 < 2; nn2++) {
        int no = nn2 * 32 + lg * 8;
        bf16x8 Ah[4], Al[4];
        #pragma unroll
        for (int kt2 = 0; kt2 < 4; kt2++) {
            Ah[kt2] = *(bf16x8*)&sTh[(kt2 * 16 + lr) * SP + no];
            Al[kt2] = *(bf16x8*)&sTl[(kt2 * 16 + lr) * SP + no];
        }
        #pragma unroll
        for (int cio = 0; cio < 2; cio++) {
            int c = (w * 2 + cio) * 16 + lr;
            size_t go = ((size_t)(b * C + c)) * NN + n0 + no;
            bf16x8 Bh = *(const bf16x8*)&xch[go];
            bf16x8 Bl = *(const bf16x8*)&xcl[go];
            #pragma unroll
            for (int kt2 = 0; kt2 < 4; kt2++) {
                macc[kt2 * 2 + cio] = __builtin_amdgcn_mfma_f32_16x16x32_bf16(Ah[kt2], Bh, macc[kt2 * 2 + cio], 0, 0, 0);
                macc[kt2 * 2 + cio] = __builtin_amdgcn_mfma_f32_16x16x32_bf16(Al[kt2], Bh, macc[kt2 * 2 + cio], 0, 0, 0);
                macc[kt2 * 2 + cio] = __builtin_amdgcn_mfma_f32_16x16x32_bf16(Ah[kt2], Bl, macc[kt2 * 2 + cio], 0, 0, 0);
            }
        }
    }
    #pragma unroll
    for (int kt2 = 0; kt2 < 4; kt2++)
        #pragma unroll
        for (int cio = 0; cio < 2; cio++)
            #pragma unroll
            for (int jj = 0; jj < 4; jj++) {
                int kk = kt2 * 16 + lg * 4 + jj;
                int c = (w * 2 + cio) * 16 + lr;
                atomicAdd(&tp_cur[((size_t)b * K + kk) * C + c], macc[kt2 * 2 + cio][jj]);
            }
}

// ================= final norm + P(scale2) + mu output =================
// grid (4, B), block 256, dynamic LDS 67,840 B
__global__ __launch_bounds__(256) void k_pfinal(
        const float* __restrict__ tp_last, const float* __restrict__ dpart,
        const u16* __restrict__ wch, const u16* __restrict__ wcl,
        u16* __restrict__ Pb, float* __restrict__ out_mu, float dconst)
{
    extern __shared__ char smem[];
    u16* smh = (u16*)smem;
    u16* sml = smh + 64 * CP;
    float* redf = (float*)(sml + 64 * CP);
    int ob = blockIdx.x, b = blockIdx.y, tid = threadIdx.x;
    int w = tid >> 6, l = tid & 63, lg = l >> 4, lr = l & 15;
    if (tid < 64) {
        float dv = 0.f;
        #pragma unroll 8
        for (int c2 = 0; c2 < 64; c2++) dv += dpart[((size_t)(b * 64 + c2)) * K + tid];
        redf[tid] = dv;
    }
    __syncthreads();
    {
        int kq = tid >> 2, g = tid & 3;   // 64 c per thread
        const float* tp = tp_last + (size_t)b * K * C + (size_t)kq * C + g * 64;
        float vals[64];
        float ssq = 0.f;
        #pragma unroll
        for (int j4 = 0; j4 < 16; j4++) {
            float4 v4 = *(const float4*)&tp[j4 * 4];
            vals[j4 * 4 + 0] = v4.x; vals[j4 * 4 + 1] = v4.y;
            vals[j4 * 4 + 2] = v4.z; vals[j4 * 4 + 3] = v4.w;
            ssq += v4.x * v4.x + v4.y * v4.y + v4.z * v4.z + v4.w * v4.w;
        }
        ssq += __shfl_xor(ssq, 1);
        ssq += __shfl_xor(ssq, 2);
        float d = dconst + redf[kq];
        float inv = 1.f / (1e-6f * d + sqrtf(ssq));
        #pragma unroll
        for (int j8 = 0; j8 < 8; j8++) {
            u16x8 hv, lv;
            #pragma unroll
            for (int j = 0; j < 8; j++) {
                float v = vals[j8 * 8 + j] * inv;
                u16 hh = bf_hi(v);
                hv[j] = hh; lv[j] = bf_hi(v - bf_f(hh));
            }
            *(u16x8*)&smh[kq * CP + g * 64 + j8 * 8] = hv;
            *(u16x8*)&sml[kq * CP + g * 64 + j8 * 8] = lv;
        }
        if (ob == 0) {
            #pragma unroll 8
            for (int j = 0; j < 64; j++)
                out_mu[((size_t)(b * C + g * 64 + j)) * K + kq] = vals[j] * inv;
        }
    }
    __syncthreads();
    // P for scale 2
    f32x4 pacc[4] = {{0.f,0.f,0.f,0.f},{0.f,0.f,0.f,0.f},{0.f,0.f,0.f,0.f},{0.f,0.f,0.f,0.f}};
    int orow = ob * 64 + w * 16 + lr;
    const u16* wbh = wch + (size_t)orow * W3C + 2 * C;
    const u16* wbl = wcl + (size_t)orow * W3C + 2 * C;
    for (int cc = 0; cc < 8; cc++) {
        int co = cc * 32 + lg * 8;
        bf16x8 Ah = *(const bf16x8*)&wbh[co];
        bf16x8 Al = *(const bf16x8*)&wbl[co];
        #pragma unroll
        for (int kt = 0; kt < 4; kt++) {
            bf16x8 Bh = *(bf16x8*)&smh[(kt * 16 + lr) * CP + co];
            bf16x8 Bl = *(bf16x8*)&sml[(kt * 16 + lr) * CP + co];
            pacc[kt] = __builtin_amdgcn_mfma_f32_16x16x32_bf16(Ah, Bh, pacc[kt], 0, 0, 0);
            pacc[kt] = __builtin_amdgcn_mfma_f32_16x16x32_bf16(Al, Bh, pacc[kt], 0, 0, 0);
            pacc[kt] = __builtin_amdgcn_mfma_f32_16x16x32_bf16(Ah, Bl, pacc[kt], 0, 0, 0);
        }
    }
    #pragma unroll
    for (int kt = 0; kt < 4; kt++)
        #pragma unroll
        for (int jj = 0; jj < 4; jj++) {
            int o = ob * 64 + w * 16 + lg * 4 + jj;
            Pb[((size_t)((2 * B + b) * C + o)) * K + kt * 16 + lr] = bf_hi(pacc[kt][jj]);
        }
}

// ================= final: out = relu(w*(sum_s sig_s P_s^T + b_cat) + x) =================
__global__ __launch_bounds__(256) void k_final(
        const u16* __restrict__ sh_g, const u16* __restrict__ Pb,
        const float* __restrict__ x, const float* __restrict__ b_cat,
        const float* __restrict__ wscal, float* __restrict__ out) {
    __shared__ u16 ssig[64 * 72];
    __shared__ u16 sP[64 * 72];
    __shared__ float tbuf[64 * 68];
    int nt = blockIdx.x, ot = blockIdx.y, b = blockIdx.z;
    int n0 = nt * 64, o0 = ot * 64;
    int tid = threadIdx.x, w = tid >> 6, l = tid & 63, lg = l >> 4, lr = l & 15;
    f32x4 z4 = {0.f, 0.f, 0.f, 0.f};
    f32x4 acc[4] = {z4, z4, z4, z4};
    for (int s = 0; s < 3; s++) {
        __syncthreads();
        for (int t = tid; t < 512; t += 256) {
            int r = t >> 3, kc = (t & 7) * 8;
            *(u16x8*)&ssig[r * 72 + kc] =
                *(const u16x8*)&sh_g[(size_t)s * ((size_t)B * NN * K) + ((size_t)(b * NN + n0 + r)) * K + kc];
            *(u16x8*)&sP[r * 72 + kc] =
                *(const u16x8*)&Pb[((size_t)((s * B + b) * C + o0 + r)) * K + kc];
        }
        __syncthreads();
        #pragma unroll
        for (int kk = 0; kk < 2; kk++) {
            int ko = kk * 32 + lg * 8;
            bf16x8 A = *(bf16x8*)&ssig[(w * 16 + lr) * 72 + ko];
            #pragma unroll
            for (int oi = 0; oi < 4; oi++) {
                bf16x8 Bv = *(bf16x8*)&sP[(oi * 16 + lr) * 72 + ko];
                acc[oi] = __builtin_amdgcn_mfma_f32_16x16x32_bf16(A, Bv, acc[oi], 0, 0, 0);
            }
        }
    }
    __syncthreads();
    #pragma unroll
    for (int oi = 0; oi < 4; oi++)
        #pragma unroll
        for (int jj = 0; jj < 4; jj++)
            tbuf[(oi * 16 + lr) * 68 + (w * 16 + lg * 4 + jj)] = acc[oi][jj];
    __syncthreads();
    float wv = wscal[0];
    for (int t = tid; t < 1024; t += 256) {
        int ol = t >> 4, ck = (t & 15) * 4;
        int o = o0 + ol;
        float bc = b_cat[o];
        float4 u4 = *(float4*)&tbuf[ol * 68 + ck];
        size_t base = ((size_t)(b * C + o)) * NN + n0 + ck;
        float4 xv = *(const float4*)&x[base];
        float4 r;
        r.x = fmaxf((u4.x + bc) * wv + xv.x, 0.f);
        r.y = fmaxf((u4.y + bc) * wv + xv.y, 0.f);
        r.z = fmaxf((u4.z + bc) * wv + xv.z, 0.f);
        r.w = fmaxf((u4.w + bc) * wv + xv.w, 0.f);
        *(float4*)&out[base] = r;
    }
}

extern "C" void kernel_launch(void* const* d_in, const int* in_sizes, int n_in,
                              void* d_out, int out_size, void* d_ws, size_t ws_size,
                              hipStream_t stream) {
    const float* x     = (const float*)d_in[0];
    const float* mu0   = (const float*)d_in[1];
    const float* wsc   = (const float*)d_in[2];
    const float* w_cat = (const float*)d_in[3];
    const float* b_cat = (const float*)d_in[4];
    float* out = (float*)d_out;
    char* wsb = (char*)d_ws;

    const size_t SZ_X2   = (size_t)B * C * NN * 2;     // 8 MB
    const size_t SZ_MUT  = (size_t)B * K * C * 2;      // 128 KB
    const size_t SZ_SIGH = (size_t)3 * B * NN * K * 2; // 6 MB
    const size_t SZ_TPB  = (size_t)B * K * C * 4;      // 256 KB (one buffer)
    const size_t SZ_DP   = (size_t)B * 64 * K * 4;     // 64 KB
    const size_t SZ_PB   = (size_t)3 * B * C * K * 2;  // 384 KB
    const size_t SZ_WC   = (size_t)C * W3C * 2;        // 384 KB

    size_t off = 0;
    u16*   xch  = (u16*)(wsb + off); off += SZ_X2;
    u16*   xcl  = (u16*)(wsb + off); off += SZ_X2;
    u16*   xth  = (u16*)(wsb + off); off += SZ_X2;
    u16*   xtl  = (u16*)(wsb + off); off += SZ_X2;
    u16*   muth = (u16*)(wsb + off); off += SZ_MUT;
    u16*   mutl = (u16*)(wsb + off); off += SZ_MUT;
    u16*   sigh = (u16*)(wsb + off); off += SZ_SIGH;
    float* tpb0 = (float*)(wsb + off); off += SZ_TPB;
    float* tpb1 = (float*)(wsb + off); off += SZ_TPB;
    float* tpb2 = (float*)(wsb + off); off += SZ_TPB;
    float* dpart= (float*)(wsb + off); off += SZ_DP;
    u16*   Pb   = (u16*)(wsb + off); off += SZ_PB;
    u16*   wch  = (u16*)(wsb + off); off += SZ_WC;
    u16*   wcl  = (u16*)(wsb + off); off += SZ_WC;
    float* out_mu = out + (size_t)B * C * NN;
    float* bufs[3] = {tpb0, tpb1, tpb2};

    const int EM_LDS = 2 * 64 * CP * 2 + 64 * LGP * 4 + 2 * 64 * SP * 2 + 1152 * 4; // 108,032
    const int PF_LDS = 2 * 64 * CP * 2 + 64 * 4;                                    // 67,840
    hipFuncSetAttribute((const void*)k_em, hipFuncAttributeMaxDynamicSharedMemorySize, EM_LDS);
    hipFuncSetAttribute((const void*)k_pfinal, hipFuncAttributeMaxDynamicSharedMemorySize, PF_LDS);

    k_prep<<<2464, 256, 0, stream>>>(x, mu0, w_cat, xch, xcl, wch, wcl, muth, mutl, tpb0);
    k_prept<<<dim3(128, 8, B), dim3(32, 8), 0, stream>>>(x, xth, xtl);

    const int   pvals[3]   = {0, 1, 2};
    const float dconsts[3] = {1e-6f, 1e-6f + 11.9375f, 1e-6f + 59.4375f};

    for (int i = 0; i < 9; i++) {
        int s = i / 3;
        u16* shs = sigh + (size_t)s * ((size_t)B * NN * K);
        float dprev = (i > 0) ? dconsts[(i - 1) / 3] : 0.f;
        int s_prev = (i > 0 && i % 3 == 0) ? (i / 3 - 1) : -1;
        k_em<<<dim3(64, B), 512, EM_LDS, stream>>>(
            xth, xtl, xch, xcl, muth, mutl,
            bufs[(i + 2) % 3], bufs[i % 3], bufs[(i + 1) % 3], dpart,
            shs, Pb, wch, wcl,
            i, pvals[s], dprev, (i % 3 == 2) ? 1 : 0, s_prev);
    }
    k_pfinal<<<dim3(4, B), 256, PF_LDS, stream>>>(bufs[8 % 3], dpart, wch, wcl,
                                                  Pb, out_mu, dconsts[2]);
    k_final<<<dim3(64, 4, B), 256, 0, stream>>>(sigh, Pb, x, b_cat, wsc, out);
}